// Round 1
// baseline (6395.753 us; speedup 1.0000x reference)
//
#include <hip/hip_runtime.h>

// GRU L=512 steps, N=64 batch, H=512 hidden, E=256 embed, K=H+E=768.
// Design: persistent column-split kernel. 32 blocks x 256 threads (4 waves).
//  - block b owns output columns [16b, 16b+16) of z, r, h_tilde.
//  - weight slices (3 gates x 768 x 16 cols, fp16) live in LDS (73728 B),
//    XOR-swizzled to kill the 16-way bank conflict of stride-1536B col reads.
//  - per step: phase1 computes z,r (per-wave: 2 MFMA chains over K=768,
//    M=64 full), writes r*h (fp16) to a global exchange buffer; grid barrier;
//    phase2 computes h_tilde, h_new; writes h (fp16 exchange + f32 out);
//    grid barrier. 2 barriers/step, monotone-counter spin with agent-scope
//    release/acquire (cross-XCD L2 coherence per G16).
//  - numerics: fp16 operands, f32 MFMA accum, f32 hidden state -> predicted
//    absmax ~3e-3 vs 1.5e-2 threshold (bf16 would random-walk to ~1e-2).

#define LSTEPS 512
#define NBATCH 64
#define HDIM   512
#define EDIM   256
#define KDIM   768
#define NBLK   32
#define TPB    256

typedef _Float16 f16x8 __attribute__((ext_vector_type(8)));
typedef float    f32x4 __attribute__((ext_vector_type(4)));

__device__ __forceinline__ float sigm(float x){ return 1.0f/(1.0f+__expf(-x)); }
__device__ __forceinline__ float tanh_fast(float x){
  float e = __expf(2.0f*x);
  return 1.0f - 2.0f/(e + 1.0f);
}

// Transpose+convert weights: wbuf[g][j][k] = fp16(W_g[k][j]); g in {z,r,h}.
__global__ void prep_w(const float* __restrict__ Wz, const float* __restrict__ Wr,
                       const float* __restrict__ Wh, _Float16* __restrict__ wbuf){
  int tid = blockIdx.x*256 + threadIdx.x;        // 3*512*768 = 1179648 threads
  int g   = tid / (HDIM*KDIM);
  int rem = tid - g*(HDIM*KDIM);
  int j   = rem / KDIM;
  int k   = rem - j*KDIM;
  const float* W = (g==0) ? Wz : ((g==1) ? Wr : Wh);
  wbuf[tid] = (_Float16)W[(size_t)k*HDIM + j];
}

// Gather embedding rows + convert: ebuf[t][n][k] = fp16(emb[x[t][n]][k]).
__global__ void prep_emb(const int* __restrict__ x, const float* __restrict__ emb,
                         _Float16* __restrict__ ebuf){
  int tid = blockIdx.x*256 + threadIdx.x;        // one float4 each; 2097152 total
  int k4  = tid & 63;                            // E/4 = 64
  int tn  = tid >> 6;                            // 0..L*N-1
  int row = x[tn];
  const float4 v = *(const float4*)(emb + (size_t)row*EDIM + (k4<<2));
  union { _Float16 h[4]; uint2 u; } p;
  p.h[0] = (_Float16)v.x; p.h[1] = (_Float16)v.y;
  p.h[2] = (_Float16)v.z; p.h[3] = (_Float16)v.w;
  *(uint2*)(ebuf + (size_t)tn*EDIM + (k4<<2)) = p.u;
}

// Monotone-counter grid barrier (counter zeroed by memset each launch).
__device__ __forceinline__ void gbar(unsigned* cnt, unsigned target){
  __syncthreads();                               // all waves' stores complete (vmcnt drain)
  if (threadIdx.x == 0){
    __hip_atomic_fetch_add(cnt, 1u, __ATOMIC_RELEASE, __HIP_MEMORY_SCOPE_AGENT);
    while (__hip_atomic_load(cnt, __ATOMIC_RELAXED, __HIP_MEMORY_SCOPE_AGENT) < target){}
    __builtin_amdgcn_fence(__ATOMIC_ACQUIRE, "agent");  // invalidate stale L1/L2
  }
  __syncthreads();
}

__global__ __launch_bounds__(TPB) void gru_persist(
    const _Float16* __restrict__ wbuf,   // [3][512][768] fp16 (col-major per gate)
    const _Float16* __restrict__ ebuf,   // [L][64][256] fp16
    const float* __restrict__ bz, const float* __restrict__ br, const float* __restrict__ bh,
    _Float16* __restrict__ hbuf,         // [64][512] fp16 exchange (h)
    _Float16* __restrict__ rhbuf,        // [64][512] fp16 exchange (r*h)
    float* __restrict__ hf,              // [64][512] f32 state (block-column-private)
    float* __restrict__ out,             // [L][64][512] f32
    unsigned* __restrict__ cnt)
{
  __shared__ char wlds[3*16*1536];       // 73728 B: [gate][col16][768 fp16]
  const int jbase = blockIdx.x * 16;

  // Stage weight slices -> LDS. Linear addr then XOR-swizzle bits 4..6 by col.
  for (int cidx = threadIdx.x; cidx < 3*16*96; cidx += TPB){
    int g   = cidx / (16*96);
    int rem = cidx - g*(16*96);
    int col = rem / 96;
    int kch = rem - col*96;              // 16B chunk index along K (8 fp16)
    const uint4 v = *(const uint4*)(wbuf + ((size_t)(g*HDIM + jbase + col))*KDIM + kch*8);
    int off = (((g*16 + col)*1536) + kch*16) ^ ((col & 7) << 4);
    *(uint4*)(wlds + off) = v;
  }
  __syncthreads();

  const int lane = threadIdx.x & 63;
  const int wave = threadIdx.x >> 6;     // 0..3 = M-tile
  const int c15  = lane & 15;
  const int kgrp = lane >> 4;
  const int jcol = jbase + c15;
  const int mt   = wave;
  const int arow = mt*16 + c15;          // A-fragment row (batch)
  const int n0   = mt*16 + kgrp*4;       // C/D row base (batch)
  const int swz  = (c15 & 7) << 4;
  const int linz = (( 0*16 + c15)*1536) + kgrp*16;   // linear LDS base, gate z
  const int linr = ((1*16 + c15)*1536) + kgrp*16;    // gate r
  const int linh = ((2*16 + c15)*1536) + kgrp*16;    // gate h
  const float bzj = bz[jcol];
  const float brj = br[jcol];
  const float bhj = bh[jcol];

  unsigned gen = 0;
  for (int t = 0; t < LSTEPS; ++t){
    const _Float16* et = ebuf + (size_t)t*(NBATCH*EDIM);

    // ---------- phase 1: z, r (A = [h, e], B = Wz|Wr slices) ----------
    f32x4 accz = {0.f,0.f,0.f,0.f};
    f32x4 accr = {0.f,0.f,0.f,0.f};
    {
      const _Float16* ah = hbuf + arow*HDIM + kgrp*8;
      const _Float16* ae = et   + arow*EDIM + kgrp*8;
      #pragma unroll
      for (int kc = 0; kc < 16; ++kc){
        f16x8 a  = *(const f16x8*)(ah + kc*32);
        f16x8 bzv = *(const f16x8*)(wlds + ((linz + kc*64) ^ swz));
        f16x8 brv = *(const f16x8*)(wlds + ((linr + kc*64) ^ swz));
        accz = __builtin_amdgcn_mfma_f32_16x16x32_f16(a, bzv, accz, 0, 0, 0);
        accr = __builtin_amdgcn_mfma_f32_16x16x32_f16(a, brv, accr, 0, 0, 0);
      }
      #pragma unroll
      for (int kc = 0; kc < 8; ++kc){
        f16x8 a  = *(const f16x8*)(ae + kc*32);
        f16x8 bzv = *(const f16x8*)(wlds + ((linz + (16+kc)*64) ^ swz));
        f16x8 brv = *(const f16x8*)(wlds + ((linr + (16+kc)*64) ^ swz));
        accz = __builtin_amdgcn_mfma_f32_16x16x32_f16(a, bzv, accz, 0, 0, 0);
        accr = __builtin_amdgcn_mfma_f32_16x16x32_f16(a, brv, accr, 0, 0, 0);
      }
    }
    float zreg[4];
    #pragma unroll
    for (int i = 0; i < 4; ++i){
      zreg[i]  = sigm(accz[i] + bzj);
      float r  = sigm(accr[i] + brj);
      float hp = hf[(n0+i)*HDIM + jcol];
      rhbuf[(n0+i)*HDIM + jcol] = (_Float16)(r * hp);
    }
    ++gen; gbar(cnt, NBLK*gen);

    // ---------- phase 2: h_tilde, h_new (A = [r*h, e], B = Wh slice) ----------
    f32x4 acch = {0.f,0.f,0.f,0.f};
    {
      const _Float16* ar = rhbuf + arow*HDIM + kgrp*8;
      const _Float16* ae = et    + arow*EDIM + kgrp*8;
      #pragma unroll
      for (int kc = 0; kc < 16; ++kc){
        f16x8 a  = *(const f16x8*)(ar + kc*32);
        f16x8 bh_ = *(const f16x8*)(wlds + ((linh + kc*64) ^ swz));
        acch = __builtin_amdgcn_mfma_f32_16x16x32_f16(a, bh_, acch, 0, 0, 0);
      }
      #pragma unroll
      for (int kc = 0; kc < 8; ++kc){
        f16x8 a  = *(const f16x8*)(ae + kc*32);
        f16x8 bh_ = *(const f16x8*)(wlds + ((linh + (16+kc)*64) ^ swz));
        acch = __builtin_amdgcn_mfma_f32_16x16x32_f16(a, bh_, acch, 0, 0, 0);
      }
    }
    #pragma unroll
    for (int i = 0; i < 4; ++i){
      float ht = tanh_fast(acch[i] + bhj);
      int   n  = n0 + i;
      float hp = hf[n*HDIM + jcol];
      float hn = hp + zreg[i]*(ht - hp);      // (1-z)h + z*h~
      out[((size_t)t*NBATCH + n)*HDIM + jcol] = hn;
      hf[n*HDIM + jcol]   = hn;
      hbuf[n*HDIM + jcol] = (_Float16)hn;
    }
    ++gen; gbar(cnt, NBLK*gen);
  }
}

extern "C" void kernel_launch(void* const* d_in, const int* in_sizes, int n_in,
                              void* d_out, int out_size, void* d_ws, size_t ws_size,
                              hipStream_t stream) {
  const int*   x   = (const int*)  d_in[0];
  const float* emb = (const float*)d_in[1];
  const float* Wz  = (const float*)d_in[2];
  const float* bz  = (const float*)d_in[3];
  const float* Wr  = (const float*)d_in[4];
  const float* br  = (const float*)d_in[5];
  const float* Wh  = (const float*)d_in[6];
  const float* bh  = (const float*)d_in[7];
  float* out = (float*)d_out;
  char*  ws  = (char*)d_ws;

  // Workspace layout (16B-aligned slabs), total ~18.5 MB:
  size_t off = 0;
  unsigned*  cnt   = (unsigned*)(ws + off); off += 256;
  float*     hf    = (float*)   (ws + off); off += (size_t)NBATCH*HDIM*4;   // 131072
  _Float16*  hbuf  = (_Float16*)(ws + off); off += (size_t)NBATCH*HDIM*2;   // 65536
  size_t zero_bytes = off;                  // cnt + hf + hbuf must start at 0
  _Float16*  rhbuf = (_Float16*)(ws + off); off += (size_t)NBATCH*HDIM*2;   // 65536
  _Float16*  wbuf  = (_Float16*)(ws + off); off += (size_t)3*HDIM*KDIM*2;   // 2359296
  _Float16*  ebuf  = (_Float16*)(ws + off); off += (size_t)LSTEPS*NBATCH*EDIM*2; // 16777216

  hipMemsetAsync(ws, 0, zero_bytes, stream);

  prep_w  <<<(3*HDIM*KDIM)/256,          256, 0, stream>>>(Wz, Wr, Wh, wbuf);
  prep_emb<<<(LSTEPS*NBATCH*EDIM/4)/256, 256, 0, stream>>>(x, emb, ebuf);
  gru_persist<<<NBLK, TPB, 0, stream>>>(wbuf, ebuf, bz, br, bh,
                                        hbuf, rhbuf, hf, out, cnt);
}

// Round 2
// 5934.160 us; speedup vs baseline: 1.0778x; 1.0778x over previous
//
#include <hip/hip_runtime.h>

// GRU L=512, N=64, H=512, E=256, K=H+E=768. Persistent column-split kernel:
// 32 blocks x 256 threads; block b owns 16 output columns of z/r/h~ with its
// fp16 weight slice LDS-resident (73.7 KB, XOR-swizzled). Round 2: replaced
// the contended atomic-counter grid barrier with per-block release flags +
// lane-parallel polling, write-through (agent-scope atomic) exchange stores,
// e-part MFMA chains overlapped with the flag waits, and register-resident
// hidden state. Numerics: fp16 operands, f32 MFMA accum, f32 state
// (round-1 measured absmax 3.9e-3 vs 1.5e-2 threshold).

#define LSTEPS 512
#define NBATCH 64
#define HDIM   512
#define EDIM   256
#define KDIM   768
#define NBLK   32
#define TPB    256

typedef _Float16 f16x8 __attribute__((ext_vector_type(8)));
typedef float    f32x4 __attribute__((ext_vector_type(4)));

__device__ __forceinline__ float sigm(float x){ return 1.0f/(1.0f+__expf(-x)); }
__device__ __forceinline__ float tanh_fast(float x){
  float e = __expf(2.0f*x);
  return 1.0f - 2.0f/(e + 1.0f);
}
__device__ __forceinline__ unsigned f16b(float x){
  union { _Float16 h; unsigned short u; } c; c.h = (_Float16)x; return (unsigned)c.u;
}

// Transpose+convert weights: wbuf[g][j][k] = fp16(W_g[k][j]); g in {z,r,h}.
__global__ void prep_w(const float* __restrict__ Wz, const float* __restrict__ Wr,
                       const float* __restrict__ Wh, _Float16* __restrict__ wbuf){
  int tid = blockIdx.x*256 + threadIdx.x;        // 3*512*768 = 1179648 threads
  int g   = tid / (HDIM*KDIM);
  int rem = tid - g*(HDIM*KDIM);
  int j   = rem / KDIM;
  int k   = rem - j*KDIM;
  const float* W = (g==0) ? Wz : ((g==1) ? Wr : Wh);
  wbuf[tid] = (_Float16)W[(size_t)k*HDIM + j];
}

// Gather embedding rows + convert: ebuf[t][n][k] = fp16(emb[x[t][n]][k]).
__global__ void prep_emb(const int* __restrict__ x, const float* __restrict__ emb,
                         _Float16* __restrict__ ebuf){
  int tid = blockIdx.x*256 + threadIdx.x;        // one float4 each
  int k4  = tid & 63;                            // E/4 = 64
  int tn  = tid >> 6;                            // 0..L*N-1
  int row = x[tn];
  const float4 v = *(const float4*)(emb + (size_t)row*EDIM + (k4<<2));
  union { _Float16 h[4]; uint2 u; } p;
  p.h[0] = (_Float16)v.x; p.h[1] = (_Float16)v.y;
  p.h[2] = (_Float16)v.z; p.h[3] = (_Float16)v.w;
  *(uint2*)(ebuf + (size_t)tn*EDIM + (k4<<2)) = p.u;
}

// Wait until every block's flag >= target. Lane l polls flag[l]; no RMW,
// no shared hot line mutation. Acquire fence pairs with producers' release
// stores and invalidates stale L1/L2 so normal vector loads see fresh data.
__device__ __forceinline__ void wait_flags(unsigned* flags, unsigned target){
  const int l = threadIdx.x & 63;
  for (;;){
    unsigned v = target;
    if (l < NBLK) v = __hip_atomic_load(&flags[l], __ATOMIC_RELAXED, __HIP_MEMORY_SCOPE_AGENT);
    if (__all(v >= target)) break;
  }
  __builtin_amdgcn_fence(__ATOMIC_ACQUIRE, "agent");
}

// Exchange store of (rows n0..n0+3, col jcol) as write-through 4B atomics.
// Lane pair (2q,2q+1) covers cols (j,j+1): shfl_xor repack -> even lane
// stores rows n0+0..1, odd lane rows n0+2..3, each as one aligned dword.
__device__ __forceinline__ void store_x(_Float16* buf, int jc2, int n0, int lane,
                                        float v0, float v1, float v2, float v3){
  unsigned p01 = f16b(v0) | (f16b(v1) << 16);
  unsigned p23 = f16b(v2) | (f16b(v3) << 16);
  unsigned q01 = __shfl_xor(p01, 1, 64);
  unsigned q23 = __shfl_xor(p23, 1, 64);
  unsigned w0, w1; int r0;
  if (lane & 1){                       // own col = jc2+1 (high half)
    w0 = (q23 & 0xffffu) | (p23 << 16);
    w1 = (q23 >> 16)     | (p23 & 0xffff0000u);
    r0 = n0 + 2;
  } else {                             // own col = jc2 (low half)
    w0 = (p01 & 0xffffu) | (q01 << 16);
    w1 = (p01 >> 16)     | (q01 & 0xffff0000u);
    r0 = n0;
  }
  __hip_atomic_store((unsigned*)(buf + (size_t)r0*HDIM + jc2),     w0,
                     __ATOMIC_RELAXED, __HIP_MEMORY_SCOPE_AGENT);
  __hip_atomic_store((unsigned*)(buf + (size_t)(r0+1)*HDIM + jc2), w1,
                     __ATOMIC_RELAXED, __HIP_MEMORY_SCOPE_AGENT);
}

__global__ __launch_bounds__(TPB) void gru_persist(
    const _Float16* __restrict__ wbuf,   // [3][512][768] fp16 (col-major per gate)
    const _Float16* __restrict__ ebuf,   // [L][64][256] fp16
    const float* __restrict__ bz, const float* __restrict__ br, const float* __restrict__ bh,
    _Float16* __restrict__ hbuf,         // [64][512] fp16 exchange (h)
    _Float16* __restrict__ rhbuf,        // [64][512] fp16 exchange (r*h)
    float* __restrict__ out,             // [L][64][512] f32
    unsigned* __restrict__ flags)        // [NBLK] generation flags
{
  __shared__ char wlds[3*16*1536];       // 73728 B: [gate][col16][768 fp16]
  const int jbase = blockIdx.x * 16;

  // Stage weight slices -> LDS, XOR-swizzled by col to spread banks.
  for (int cidx = threadIdx.x; cidx < 3*16*96; cidx += TPB){
    int g   = cidx / (16*96);
    int rem = cidx - g*(16*96);
    int col = rem / 96;
    int kch = rem - col*96;              // 16B chunk index along K
    const uint4 v = *(const uint4*)(wbuf + ((size_t)(g*HDIM + jbase + col))*KDIM + kch*8);
    int off = (((g*16 + col)*1536) + kch*16) ^ ((col & 7) << 4);
    *(uint4*)(wlds + off) = v;
  }
  __syncthreads();

  const int lane = threadIdx.x & 63;
  const int wave = threadIdx.x >> 6;     // M-tile
  const int c15  = lane & 15;
  const int kgrp = lane >> 4;
  const int jcol = jbase + c15;
  const int jc2  = jcol & ~1;
  const int arow = wave*16 + c15;        // A-fragment row (batch)
  const int n0   = wave*16 + kgrp*4;     // C/D row base (batch)
  const int swz  = (c15 & 7) << 4;
  const int linz = ((      c15)*1536) + kgrp*16;
  const int linr = ((16  + c15)*1536) + kgrp*16;
  const int linh = ((32  + c15)*1536) + kgrp*16;
  const float bzj = bz[jcol];
  const float brj = br[jcol];
  const float bhj = bh[jcol];
  float hreg[4] = {0.f, 0.f, 0.f, 0.f};  // private f32 hidden state

  unsigned gen = 0;
  for (int t = 0; t < LSTEPS; ++t){
    const _Float16* et = ebuf + (size_t)t*(NBATCH*EDIM);
    const _Float16* ae = et + arow*EDIM + kgrp*8;

    // ---- phase 1: z, r. e-part first (no exchange dep) to overlap the wait.
    f32x4 accz = {0.f,0.f,0.f,0.f};
    f32x4 accr = {0.f,0.f,0.f,0.f};
    #pragma unroll
    for (int kc = 0; kc < 8; ++kc){
      f16x8 a   = *(const f16x8*)(ae + kc*32);
      f16x8 bzv = *(const f16x8*)(wlds + ((linz + (16+kc)*64) ^ swz));
      f16x8 brv = *(const f16x8*)(wlds + ((linr + (16+kc)*64) ^ swz));
      accz = __builtin_amdgcn_mfma_f32_16x16x32_f16(a, bzv, accz, 0, 0, 0);
      accr = __builtin_amdgcn_mfma_f32_16x16x32_f16(a, brv, accr, 0, 0, 0);
    }
    wait_flags(flags, gen);              // h(t-1) from all blocks visible
    {
      const _Float16* ah = hbuf + arow*HDIM + kgrp*8;
      #pragma unroll
      for (int kc = 0; kc < 16; ++kc){
        f16x8 a   = *(const f16x8*)(ah + kc*32);
        f16x8 bzv = *(const f16x8*)(wlds + ((linz + kc*64) ^ swz));
        f16x8 brv = *(const f16x8*)(wlds + ((linr + kc*64) ^ swz));
        accz = __builtin_amdgcn_mfma_f32_16x16x32_f16(a, bzv, accz, 0, 0, 0);
        accr = __builtin_amdgcn_mfma_f32_16x16x32_f16(a, brv, accr, 0, 0, 0);
      }
    }
    float zreg[4], rh[4];
    #pragma unroll
    for (int i = 0; i < 4; ++i){
      zreg[i] = sigm(accz[i] + bzj);
      rh[i]   = sigm(accr[i] + brj) * hreg[i];
    }
    store_x(rhbuf, jc2, n0, lane, rh[0], rh[1], rh[2], rh[3]);
    __syncthreads();                     // all waves' rh stores drained (vmcnt)
    if (threadIdx.x == 0)
      __hip_atomic_store(&flags[blockIdx.x], gen+1,
                         __ATOMIC_RELEASE, __HIP_MEMORY_SCOPE_AGENT);

    // ---- phase 2: h~. e-part first, overlapping the rh wait.
    f32x4 acch = {0.f,0.f,0.f,0.f};
    #pragma unroll
    for (int kc = 0; kc < 8; ++kc){
      f16x8 a   = *(const f16x8*)(ae + kc*32);
      f16x8 bhv = *(const f16x8*)(wlds + ((linh + (16+kc)*64) ^ swz));
      acch = __builtin_amdgcn_mfma_f32_16x16x32_f16(a, bhv, acch, 0, 0, 0);
    }
    wait_flags(flags, gen+1);            // r*h from all blocks visible
    {
      const _Float16* ar = rhbuf + arow*HDIM + kgrp*8;
      #pragma unroll
      for (int kc = 0; kc < 16; ++kc){
        f16x8 a   = *(const f16x8*)(ar + kc*32);
        f16x8 bhv = *(const f16x8*)(wlds + ((linh + kc*64) ^ swz));
        acch = __builtin_amdgcn_mfma_f32_16x16x32_f16(a, bhv, acch, 0, 0, 0);
      }
    }
    #pragma unroll
    for (int i = 0; i < 4; ++i){
      float ht = tanh_fast(acch[i] + bhj);
      float hn = hreg[i] + zreg[i]*(ht - hreg[i]);   // (1-z)h + z*h~
      hreg[i] = hn;
      out[((size_t)t*NBATCH + (n0+i))*HDIM + jcol] = hn;
    }
    store_x(hbuf, jc2, n0, lane, hreg[0], hreg[1], hreg[2], hreg[3]);
    __syncthreads();
    if (threadIdx.x == 0)
      __hip_atomic_store(&flags[blockIdx.x], gen+2,
                         __ATOMIC_RELEASE, __HIP_MEMORY_SCOPE_AGENT);
    gen += 2;
  }
}

extern "C" void kernel_launch(void* const* d_in, const int* in_sizes, int n_in,
                              void* d_out, int out_size, void* d_ws, size_t ws_size,
                              hipStream_t stream) {
  const int*   x   = (const int*)  d_in[0];
  const float* emb = (const float*)d_in[1];
  const float* Wz  = (const float*)d_in[2];
  const float* bz  = (const float*)d_in[3];
  const float* Wr  = (const float*)d_in[4];
  const float* br  = (const float*)d_in[5];
  const float* Wh  = (const float*)d_in[6];
  const float* bh  = (const float*)d_in[7];
  float* out = (float*)d_out;
  char*  ws  = (char*)d_ws;

  size_t off = 0;
  unsigned*  flags = (unsigned*)(ws + off); off += 256;
  _Float16*  hbuf  = (_Float16*)(ws + off); off += (size_t)NBATCH*HDIM*2;   // 65536
  size_t zero_bytes = off;                  // flags + hbuf must start at 0
  _Float16*  rhbuf = (_Float16*)(ws + off); off += (size_t)NBATCH*HDIM*2;   // 65536
  _Float16*  wbuf  = (_Float16*)(ws + off); off += (size_t)3*HDIM*KDIM*2;   // 2359296
  _Float16*  ebuf  = (_Float16*)(ws + off); off += (size_t)LSTEPS*NBATCH*EDIM*2; // 16777216

  hipMemsetAsync(ws, 0, zero_bytes, stream);

  prep_w  <<<(3*HDIM*KDIM)/256,          256, 0, stream>>>(Wz, Wr, Wh, wbuf);
  prep_emb<<<(LSTEPS*NBATCH*EDIM/4)/256, 256, 0, stream>>>(x, emb, ebuf);
  gru_persist<<<NBLK, TPB, 0, stream>>>(wbuf, ebuf, bz, br, bh,
                                        hbuf, rhbuf, out, flags);
}